// Round 5
// baseline (5339.882 us; speedup 1.0000x reference)
//
#include <hip/hip_runtime.h>
#include <math.h>

#define B_    2
#define T_    2048
#define C_    1024
#define H_    16
#define HD_   64
#define E_    8
#define NTOK  4096
#define CAP_  1024
#define FOURC 4096
#define EPS_  1e-6f

typedef __attribute__((ext_vector_type(8))) short bf16x8;
typedef __attribute__((ext_vector_type(4))) float f32x4;

// ---------------- workspace layout (float offsets) ----------------
#define OFF_XR   ((size_t)0)                    // 4194304 : x' = l0*x + l1*x0
#define OFF_H    ((size_t)4194304)              // 4194304 : h = rmsnorm(x2)
#define OFF_MISC ((size_t)8388608)              // 32768   : eid/g0/slots/counts
#define OFF_A    (OFF_MISC + 32768)             // attention scratch, dead by expert phase
#define OFF_O    (OFF_A + 4194304)
#define OFF_Q    (OFF_O + 4194304)
#define OFF_K    (OFF_Q + 4194304)
#define OFF_V    (OFF_K + 4194304)
// expert phase overlays OFF_A.. : h_bf16 (2M floats) + chunk{ew1b,ew2b,h1b}

__device__ __forceinline__ float4 ld4(const float* p) { return *(const float4*)p; }

__device__ __forceinline__ unsigned short f2b(float x) {  // fp32 -> bf16 RNE
  unsigned int u = __float_as_uint(x);
  u = (u + 0x7FFFu + ((u >> 16) & 1u)) >> 16;
  return (unsigned short)u;
}

// ---------------- fused (optional mix) + rmsnorm ----------------
__global__ __launch_bounds__(256)
void k_norm(const float* __restrict__ in, const float* __restrict__ in2,
            const float* __restrict__ lambdas,
            float* __restrict__ rawOut, float* __restrict__ normOut) {
  const int row = blockIdx.x;
  const int t = threadIdx.x;
  const size_t base = (size_t)row * C_ + t * 4;
  float4 v = ld4(in + base);
  float4 m;
  if (in2 != nullptr) {
    const float l0 = lambdas[0], l1 = lambdas[1];
    float4 v2 = ld4(in2 + base);
    m.x = l0 * v.x + l1 * v2.x;
    m.y = l0 * v.y + l1 * v2.y;
    m.z = l0 * v.z + l1 * v2.z;
    m.w = l0 * v.w + l1 * v2.w;
  } else {
    m = v;
  }
  float ss = m.x * m.x + m.y * m.y + m.z * m.z + m.w * m.w;
  #pragma unroll
  for (int off = 32; off > 0; off >>= 1) ss += __shfl_xor(ss, off);
  __shared__ float red[4];
  if ((t & 63) == 0) red[t >> 6] = ss;
  __syncthreads();
  const float tot = red[0] + red[1] + red[2] + red[3];
  const float inv = 1.0f / sqrtf(tot * (1.0f / C_) + EPS_);
  if (rawOut != nullptr) *(float4*)(rawOut + base) = m;
  float4 nm;
  nm.x = m.x * inv; nm.y = m.y * inv; nm.z = m.z * inv; nm.w = m.w * inv;
  *(float4*)(normOut + base) = nm;
}

// ---------------- fp32 NT-GEMM (qkv / c_proj only) ----------------
#define BM 128
#define BN 128
#define BK 16
#define PA 132

template<int MODE>   // 0: qkv scatter, 1: c_proj + bias + resid
__global__ __launch_bounds__(256, 2)
void k_gemm(const float* __restrict__ Ag, const float* __restrict__ Bg,
            float* __restrict__ Cg, int Kd, int lda, int ldb,
            const float* __restrict__ bias, const float* __restrict__ resid,
            float* __restrict__ oq, float* __restrict__ ok, float* __restrict__ ov) {
  __shared__ float As[BK * PA];
  __shared__ float Bs[BK * PA];

  const int tid = threadIdx.x;
  const int n0 = blockIdx.x * BN;
  const int m0 = blockIdx.y * BM;

  const int r = tid >> 2;            // 0..63
  const int f4 = (tid & 3) * 4;      // 0,4,8,12

  const float* pa0 = Ag + (size_t)(m0 + r) * lda + f4;
  const float* pa1 = Ag + (size_t)(m0 + r + 64) * lda + f4;
  const float* pb0 = Bg + (size_t)(n0 + r) * ldb + f4;
  const float* pb1 = Bg + (size_t)(n0 + r + 64) * ldb + f4;

  float4 ga0, ga1, gb0, gb1;
  const int nkt = Kd >> 4;

  ga0 = ld4(pa0); ga1 = ld4(pa1); gb0 = ld4(pb0); gb1 = ld4(pb1);

  const int tx = tid & 15, ty = tid >> 4;
  float acc[8][8];
  #pragma unroll
  for (int i = 0; i < 8; i++)
    #pragma unroll
    for (int j = 0; j < 8; j++) acc[i][j] = 0.f;

  for (int kt = 0; kt < nkt; kt++) {
    __syncthreads();
    #pragma unroll
    for (int l = 0; l < 4; l++) {
      As[(f4 + l) * PA + r]      = (&ga0.x)[l];
      As[(f4 + l) * PA + r + 64] = (&ga1.x)[l];
      Bs[(f4 + l) * PA + r]      = (&gb0.x)[l];
      Bs[(f4 + l) * PA + r + 64] = (&gb1.x)[l];
    }
    __syncthreads();
    if (kt + 1 < nkt) {
      const int k0 = (kt + 1) * BK;
      ga0 = ld4(pa0 + k0); ga1 = ld4(pa1 + k0);
      gb0 = ld4(pb0 + k0); gb1 = ld4(pb1 + k0);
    }
    #pragma unroll
    for (int kk = 0; kk < BK; kk++) {
      float4 a0 = *(float4*)&As[kk * PA + ty * 4];
      float4 a1 = *(float4*)&As[kk * PA + ty * 4 + 64];
      float4 b0 = *(float4*)&Bs[kk * PA + tx * 4];
      float4 b1 = *(float4*)&Bs[kk * PA + tx * 4 + 64];
      float av[8] = {a0.x, a0.y, a0.z, a0.w, a1.x, a1.y, a1.z, a1.w};
      float bv[8] = {b0.x, b0.y, b0.z, b0.w, b1.x, b1.y, b1.z, b1.w};
      #pragma unroll
      for (int i = 0; i < 8; i++)
        #pragma unroll
        for (int j = 0; j < 8; j++) acc[i][j] += av[i] * bv[j];
    }
  }

  #pragma unroll
  for (int ih = 0; ih < 2; ih++) {
    #pragma unroll
    for (int ii = 0; ii < 4; ii++) {
      const int i = ih * 4 + ii;
      const int m = m0 + ty * 4 + ii + ih * 64;
      #pragma unroll
      for (int jh = 0; jh < 2; jh++) {
        const int n = n0 + tx * 4 + jh * 64;
        float4 vv = make_float4(acc[i][jh * 4 + 0], acc[i][jh * 4 + 1],
                                acc[i][jh * 4 + 2], acc[i][jh * 4 + 3]);
        if (MODE == 0) {
          const int kap = n >> 10;
          const int hh = (n >> 6) & 15;
          const int d = n & 63;
          const int bq = m >> 11, tq = m & 2047;
          float* dst = (kap == 0) ? oq : ((kap == 1) ? ok : ov);
          *(float4*)(dst + ((size_t)((bq * 16 + hh) * 2048 + tq)) * 64 + d) = vv;
        } else {
          float4 bb = ld4(bias + n);
          float4 rr = ld4(resid + (size_t)m * C_ + n);
          vv.x += bb.x + rr.x; vv.y += bb.y + rr.y;
          vv.z += bb.z + rr.z; vv.w += bb.w + rr.w;
          *(float4*)(Cg + (size_t)m * C_ + n) = vv;
        }
      }
    }
  }
}

// ---------------- q/k rmsnorm + rotary ----------------
__global__ __launch_bounds__(256)
void k_qkrot(float* __restrict__ qb, float* __restrict__ kb) {
  const int w = threadIdx.x >> 6, lane = threadIdx.x & 63;
  const int row = blockIdx.x * 4 + w;
  float* buf = (blockIdx.y == 0) ? qb : kb;
  const int t = row & 2047;
  float val = buf[(size_t)row * 64 + lane];
  float ss = val * val;
  #pragma unroll
  for (int off = 32; off > 0; off >>= 1) ss += __shfl_xor(ss, off);
  const float nrm = val / sqrtf(ss * (1.0f / 64.0f) + EPS_);
  const int i = lane & 31;
  float c, s;
  if (i < 16) {
    const float y = (float)i * (1.0f / 15.0f);
    const float inv = exp2f(-10.0f * y);           // (1/1024)^y
    const float ang = (float)t * inv;
    c = cosf(ang); s = sinf(ang);
  } else { c = 1.0f; s = 0.0f; }
  const float partner = __shfl_xor(nrm, 32);
  const float out = (lane < 32) ? (nrm * c + partner * s) : (partner * (-s) + nrm * c);
  buf[(size_t)row * 64 + lane] = out;
}

// ---------------- causal flash attention, fp32, 4x4 register tiles ----------------
// 256 thr = 4 waves; wave owns 16 rows; per-lane 4x4 micro-tile:
//   scores: lane=(rq=lane>>4, jq=lane&15) owns S[4 rows][4 keys]
//   PV:     lane=(rq, dq=lane&15) owns O[4 rows][4 dims]
// 8 ds_read_b128 per 64 FMAs, 16 independent acc chains.
// Fixed-max softmax (|s|<=8 exact): p = exp(s-8), denominators deferred.
// All LDS tiles swizzled: element (r,c) at r*64 + ((c>>2 ^ ((r>>2)&7))<<2) + (c&3).
__global__ __launch_bounds__(256, 2)
void k_attn(const float* __restrict__ q, const float* __restrict__ k,
            const float* __restrict__ v, float* __restrict__ o) {
  const int gid = blockIdx.x;          // 0..1023
  const int rg = 31 - (gid >> 5);      // heavy blocks (many tiles) dispatched first
  const int bh = gid & 31;
  const int tid = threadIdx.x;
  const int w = tid >> 6, lane = tid & 63;
  const int rq = lane >> 4;            // row quad within wave's 16 rows
  const int cq = lane & 15;            // key-quad (scores) / dim-quad (PV)
  __shared__ float qs[64 * 64];
  __shared__ float Ks[64 * 64];
  __shared__ float Vt[64 * 64];        // Vt[d][j]
  __shared__ float ps[64 * 64];
  const size_t base = (size_t)bh * (T_ * HD_);
  const int row0 = rg * 64;

  {  // stage q (pre-scaled by 1/sqrt(HD)), swizzled
    const int c = tid & 15;
    #pragma unroll
    for (int p = 0; p < 4; p++) {
      const int r = p * 16 + (tid >> 4);
      float4 qv = ld4(q + base + (size_t)(row0 + r) * 64 + c * 4);
      qv.x *= 0.125f; qv.y *= 0.125f; qv.z *= 0.125f; qv.w *= 0.125f;
      *(float4*)&qs[r * 64 + ((c ^ ((r >> 2) & 7)) << 2)] = qv;
    }
  }

  float oacc[4][4];
  float lsum[4];
  #pragma unroll
  for (int i = 0; i < 4; i++) {
    lsum[i] = 0.f;
    #pragma unroll
    for (int j = 0; j < 4; j++) oacc[i][j] = 0.f;
  }

  const int swzR = ((w * 4 + rq) & 7);   // row-side swizzle for qs/ps reads
  const int swzC = (cq & 7);             // col-side swizzle for Ks/Vt reads
  const int rbase = w * 16 + rq * 4;     // wave's local row base for this lane

  // tile-0 prefetch into regs
  float4 kpf[4], vpf[4];
  {
    const int c = tid & 15;
    #pragma unroll
    for (int p = 0; p < 4; p++) {
      const int r = p * 16 + (tid >> 4);
      kpf[p] = ld4(k + base + (size_t)r * 64 + c * 4);
      vpf[p] = ld4(v + base + (size_t)r * 64 + c * 4);
    }
  }

  for (int kt = 0; kt <= rg; kt++) {
    const int j0 = kt * 64;
    __syncthreads();   // previous tile fully consumed by all waves
    {  // write staged K / V^T from prefetch regs
      const int c = tid & 15;
      #pragma unroll
      for (int p = 0; p < 4; p++) {
        const int r = p * 16 + (tid >> 4);
        *(float4*)&Ks[r * 64 + ((c ^ ((r >> 2) & 7)) << 2)] = kpf[p];
        #pragma unroll
        for (int i = 0; i < 4; i++) {
          const int d = c * 4 + i;
          Vt[d * 64 + ((((r >> 2) ^ ((d >> 2) & 7)) << 2) | (r & 3))] = (&vpf[p].x)[i];
        }
      }
    }
    __syncthreads();
    if (kt < rg) {  // issue next tile's loads early (landing hidden under compute)
      const int c = tid & 15;
      #pragma unroll
      for (int p = 0; p < 4; p++) {
        const int r = p * 16 + (tid >> 4);
        kpf[p] = ld4(k + base + (size_t)(j0 + 64 + r) * 64 + c * 4);
        vpf[p] = ld4(v + base + (size_t)(j0 + 64 + r) * 64 + c * 4);
      }
    }

    // ---- scores: S[rbase..+3][cq*4..+3] ----
    float acc[4][4];
    #pragma unroll
    for (int i = 0; i < 4; i++)
      #pragma unroll
      for (int j = 0; j < 4; j++) acc[i][j] = 0.f;

    #pragma unroll
    for (int d4 = 0; d4 < 16; d4++) {
      float4 kk[4], qq[4];
      #pragma unroll
      for (int i = 0; i < 4; i++) {
        kk[i] = *(float4*)&Ks[(cq * 4 + i) * 64 + ((d4 ^ swzC) << 2)];
        qq[i] = *(float4*)&qs[(rbase + i) * 64 + ((d4 ^ swzR) << 2)];
      }
      #pragma unroll
      for (int ri = 0; ri < 4; ri++)
        #pragma unroll
        for (int ji = 0; ji < 4; ji++) {
          acc[ri][ji] += qq[ri].x * kk[ji].x + qq[ri].y * kk[ji].y
                       + qq[ri].z * kk[ji].z + qq[ri].w * kk[ji].w;
        }
    }

    // ---- masked exp, partial row sums, write P ----
    #pragma unroll
    for (int ri = 0; ri < 4; ri++) {
      const int r = row0 + rbase + ri;
      float4 pv;
      #pragma unroll
      for (int ji = 0; ji < 4; ji++) {
        const float p = (j0 + cq * 4 + ji <= r) ? __expf(acc[ri][ji] - 8.0f) : 0.f;
        (&pv.x)[ji] = p;
        lsum[ri] += p;
      }
      *(float4*)&ps[(rbase + ri) * 64 + ((cq ^ swzR) << 2)] = pv;
    }
    // ps is written and read by the SAME wave only (rows rbase..) -> no barrier

    // ---- PV: O[rbase..+3][cq*4..+3] += P[rows][j] * V[j][dims] ----
    #pragma unroll
    for (int jc = 0; jc < 16; jc++) {
      float4 pp[4], vv[4];
      #pragma unroll
      for (int i = 0; i < 4; i++) {
        pp[i] = *(float4*)&ps[(rbase + i) * 64 + ((jc ^ swzR) << 2)];
        vv[i] = *(float4*)&Vt[(cq * 4 + i) * 64 + ((jc ^ swzC) << 2)];
      }
      #pragma unroll
      for (int ri = 0; ri < 4; ri++)
        #pragma unroll
        for (int di = 0; di < 4; di++) {
          oacc[ri][di] += pp[ri].x * vv[di].x + pp[ri].y * vv[di].y
                        + pp[ri].z * vv[di].z + pp[ri].w * vv[di].w;
        }
    }
  }

  // reduce row sums across the 16 lanes sharing rq (lane bits 0..3)
  #pragma unroll
  for (int ri = 0; ri < 4; ri++) {
    float t2 = lsum[ri];
    #pragma unroll
    for (int off = 1; off < 16; off <<= 1) t2 += __shfl_xor(t2, off);
    lsum[ri] = t2;
  }

  const int b = bh >> 4, hh = bh & 15;
  #pragma unroll
  for (int ri = 0; ri < 4; ri++) {
    const int r = row0 + rbase + ri;
    const float inv = 1.0f / lsum[ri];
    float4 ov = make_float4(oacc[ri][0] * inv, oacc[ri][1] * inv,
                            oacc[ri][2] * inv, oacc[ri][3] * inv);
    *(float4*)(o + ((size_t)(b * 2048 + r)) * 1024 + hh * 64 + cq * 4) = ov;
  }
}

// ---------------- router ----------------
__global__ __launch_bounds__(256)
void k_router(const float* __restrict__ h, const float* __restrict__ rw,
              const float* __restrict__ rb, const float* __restrict__ nw,
              const float* __restrict__ nb, const float* __restrict__ noise,
              int* __restrict__ eid, float* __restrict__ gate0) {
  const int m = blockIdx.x;
  const int t = threadIdx.x;
  const float4 hv = ld4(h + (size_t)m * C_ + t * 4);
  float pl[E_], pn[E_];
  #pragma unroll
  for (int e2 = 0; e2 < E_; e2++) {
    float4 wv = ld4(rw + (size_t)e2 * C_ + t * 4);
    pl[e2] = hv.x * wv.x + hv.y * wv.y + hv.z * wv.z + hv.w * wv.w;
    float4 nv = ld4(nw + (size_t)e2 * C_ + t * 4);
    pn[e2] = hv.x * nv.x + hv.y * nv.y + hv.z * nv.z + hv.w * nv.w;
  }
  __shared__ float red[16][4];
  const int w = t >> 6, lane = t & 63;
  #pragma unroll
  for (int idx = 0; idx < 16; idx++) {
    float val = (idx < 8) ? pl[idx] : pn[idx - 8];
    #pragma unroll
    for (int off = 32; off > 0; off >>= 1) val += __shfl_xor(val, off);
    if (lane == 0) red[idx][w] = val;
  }
  __syncthreads();
  if (t == 0) {
    float noisy[E_];
    #pragma unroll
    for (int e2 = 0; e2 < E_; e2++) {
      const float lg = red[e2][0] + red[e2][1] + red[e2][2] + red[e2][3] + rb[e2];
      const float nl = red[8 + e2][0] + red[8 + e2][1] + red[8 + e2][2] + red[8 + e2][3] + nb[e2];
      const float sp = fmaxf(nl, 0.f) + log1pf(expf(-fabsf(nl)));
      noisy[e2] = lg + noise[m * E_ + e2] * sp;
    }
    int i0 = 0; float v0 = noisy[0];
    #pragma unroll
    for (int e2 = 1; e2 < E_; e2++)
      if (noisy[e2] > v0) { v0 = noisy[e2]; i0 = e2; }
    float v1 = -INFINITY;
    #pragma unroll
    for (int e2 = 0; e2 < E_; e2++)
      if (e2 != i0 && noisy[e2] > v1) { v1 = noisy[e2]; }
    eid[m] = i0;
    gate0[m] = 1.0f / (1.0f + expf(v1 - v0));
  }
}

// ---------------- ordered per-expert compaction ----------------
__global__ __launch_bounds__(256)
void k_assign(const int* __restrict__ eid, int* __restrict__ slots,
              int* __restrict__ counts) {
  const int t = threadIdx.x;
  int myeid[16];
  #pragma unroll
  for (int i = 0; i < 16; i++) myeid[i] = eid[t * 16 + i];
  int cnt[E_];
  #pragma unroll
  for (int e2 = 0; e2 < E_; e2++) {
    int c = 0;
    #pragma unroll
    for (int i = 0; i < 16; i++) c += (myeid[i] == e2) ? 1 : 0;
    cnt[e2] = c;
  }
  __shared__ int sc[256];
  #pragma unroll
  for (int e2 = 0; e2 < E_; e2++) {
    sc[t] = cnt[e2];
    __syncthreads();
    for (int off = 1; off < 256; off <<= 1) {
      int xv = (t >= off) ? sc[t - off] : 0;
      __syncthreads();
      sc[t] += xv;
      __syncthreads();
    }
    int rank = sc[t] - cnt[e2];
    if (t == 255) counts[e2] = sc[255];
    #pragma unroll
    for (int i = 0; i < 16; i++) {
      if (myeid[i] == e2) {
        if (rank < CAP_) slots[e2 * CAP_ + rank] = t * 16 + i;
        rank++;
      }
    }
    __syncthreads();
  }
}

// ---------------- fp32 -> bf16 cast (grid-stride over float4) ----------------
__global__ __launch_bounds__(256)
void k_cast(const float* __restrict__ in, unsigned short* __restrict__ outp, int n4) {
  for (int i = blockIdx.x * 256 + threadIdx.x; i < n4; i += gridDim.x * 256) {
    float4 vv = ld4(in + (size_t)i * 4);
    ushort4 u;
    u.x = f2b(vv.x); u.y = f2b(vv.y); u.z = f2b(vv.z); u.w = f2b(vv.w);
    *(ushort4*)(outp + (size_t)i * 4) = u;
  }
}

// ---------------- bf16 MFMA NT-GEMM for experts ----------------
template<int MODE>
__global__ __launch_bounds__(256, 4)
void k_mgemm(const unsigned short* __restrict__ Ab, const unsigned short* __restrict__ Bb,
             int Kd, int lda, int ldb,
             const float* __restrict__ bias,
             unsigned short* __restrict__ h1out, float* __restrict__ fout,
             const int* __restrict__ slots, const int* __restrict__ counts,
             const float* __restrict__ gate, int e0) {
  const int z = blockIdx.z, e = e0 + z;
  int Ne = counts[e]; if (Ne > CAP_) Ne = CAP_;
  const int m0 = blockIdx.y * 128, n0 = blockIdx.x * 128;
  if (m0 >= Ne) return;

  __shared__ __align__(16) unsigned short Asb[128 * 64];
  __shared__ __align__(16) unsigned short Bsb[128 * 64];

  const int tid = threadIdx.x, w = tid >> 6, lane = tid & 63;
  const unsigned short* Az = (MODE == 0) ? Ab : Ab + (size_t)z * CAP_ * FOURC;
  const unsigned short* Bz = Bb + (size_t)z * ((MODE == 0) ? (size_t)FOURC * C_ : (size_t)C_ * FOURC);
  const float* biasz = bias + (size_t)e * ((MODE == 0) ? FOURC : C_);

  const int rsub = lane >> 3;        // 0..7
  const int kc   = lane & 7;         // 0..7 (16B chunk)
  const int sstore = (kc ^ rsub) * 8;

  int arow[4];
  #pragma unroll
  for (int i = 0; i < 4; i++) {
    const int m = m0 + w * 32 + i * 8 + rsub;
    if (MODE == 0) arow[i] = (m < Ne) ? slots[(size_t)e * CAP_ + m] : 0;
    else           arow[i] = m;
  }

  f32x4 acc[4][4];
  #pragma unroll
  for (int mi = 0; mi < 4; mi++)
    #pragma unroll
    for (int ni = 0; ni < 4; ni++) {
      f32x4 zz = {0.f, 0.f, 0.f, 0.f};
      acc[mi][ni] = zz;
    }

  const int wr = (w >> 1) * 64, wc = (w & 1) * 64;
  const int fr = lane & 15, fq = lane >> 4;
  const int nkt = Kd >> 6;

  for (int kt = 0; kt < nkt; kt++) {
    const int kb = kt * 64;
    bf16x8 ga[4], gb[4];
    #pragma unroll
    for (int i = 0; i < 4; i++) {
      ga[i] = *(const bf16x8*)(Az + (size_t)arow[i] * lda + kb + kc * 8);
      gb[i] = *(const bf16x8*)(Bz + (size_t)(n0 + w * 32 + i * 8 + rsub) * ldb + kb + kc * 8);
    }
    __syncthreads();
    #pragma unroll
    for (int i = 0; i < 4; i++) {
      const int rowL = w * 32 + i * 8 + rsub;
      *(bf16x8*)&Asb[rowL * 64 + sstore] = ga[i];
      *(bf16x8*)&Bsb[rowL * 64 + sstore] = gb[i];
    }
    __syncthreads();
    #pragma unroll
    for (int kk = 0; kk < 2; kk++) {
      const int kcl = kk * 4 + fq;
      bf16x8 af[4], bfr[4];
      #pragma unroll
      for (int t2 = 0; t2 < 4; t2++) {
        const int rowA = wr + t2 * 16 + fr;
        af[t2]  = *(const bf16x8*)&Asb[rowA * 64 + ((kcl ^ (rowA & 7)) << 3)];
        const int rowB = wc + t2 * 16 + fr;
        bfr[t2] = *(const bf16x8*)&Bsb[rowB * 64 + ((kcl ^ (rowB & 7)) << 3)];
      }
      #pragma unroll
      for (int mi = 0; mi < 4; mi++)
        #pragma unroll
        for (int ni = 0; ni < 4; ni++)
          acc[mi][ni] = __builtin_amdgcn_mfma_f32_16x16x32_bf16(af[mi], bfr[ni], acc[mi][ni], 0, 0, 0);
    }
  }

  #pragma unroll
  for (int mi = 0; mi < 4; mi++) {
    #pragma unroll
    for (int reg = 0; reg < 4; reg++) {
      const int m = m0 + wr + mi * 16 + fq * 4 + reg;
      if (MODE == 0) {
        #pragma unroll
        for (int ni = 0; ni < 4; ni++) {
          const int n = n0 + wc + ni * 16 + fr;
          const float r = fmaxf(acc[mi][ni][reg] + biasz[n], 0.f);
          h1out[(size_t)z * CAP_ * FOURC + (size_t)m * FOURC + n] = f2b(r * r);
        }
      } else {
        const int tok = (m < Ne) ? slots[(size_t)e * CAP_ + m] : -1;
        if (tok >= 0) {
          const float gg = gate[tok];
          #pragma unroll
          for (int ni = 0; ni < 4; ni++) {
            const int n = n0 + wc + ni * 16 + fr;
            fout[(size_t)tok * C_ + n] += (acc[mi][ni][reg] + biasz[n]) * gg;
          }
        }
      }
    }
  }
}

// ---------------- launcher ----------------
extern "C" void kernel_launch(void* const* d_in, const int* in_sizes, int n_in,
                              void* d_out, int out_size, void* d_ws, size_t ws_size,
                              hipStream_t stream) {
  const float* x        = (const float*)d_in[0];
  const float* x0       = (const float*)d_in[1];
  const float* noise    = (const float*)d_in[2];
  const float* lambdas  = (const float*)d_in[3];
  // d_in[4] = lamb: (1-lamb)*v + lamb*v == v -> unused
  const float* qkv_w    = (const float*)d_in[5];
  const float* c_proj_w = (const float*)d_in[6];
  const float* c_proj_b = (const float*)d_in[7];
  const float* router_w = (const float*)d_in[8];
  const float* router_b = (const float*)d_in[9];
  const float* noise_w  = (const float*)d_in[10];
  const float* noise_b  = (const float*)d_in[11];
  const float* ew1      = (const float*)d_in[12];
  const float* eb1      = (const float*)d_in[13];
  const float* ew2      = (const float*)d_in[14];
  const float* eb2      = (const float*)d_in[15];
  float* out = (float*)d_out;
  float* ws  = (float*)d_ws;

  float* xr  = ws + OFF_XR;
  float* h   = ws + OFF_H;
  int*   eid    = (int*)(ws + OFF_MISC);
  float* gate0  = ws + OFF_MISC + 4096;
  int*   slots  = (int*)(ws + OFF_MISC + 8192);
  int*   counts = (int*)(ws + OFF_MISC + 16384);
  float* a   = ws + OFF_A;
  float* ob  = ws + OFF_O;
  float* qb  = ws + OFF_Q;
  float* kb  = ws + OFF_K;
  float* vb  = ws + OFF_V;

  // 1) x' = l0*x + l1*x0 ; a = rmsnorm(x')
  k_norm<<<NTOK, 256, 0, stream>>>(x, x0, lambdas, xr, a);
  // 2) qkv = a @ qkv_w^T, scattered into head layout
  k_gemm<0><<<dim3(24, 32), 256, 0, stream>>>(a, qkv_w, nullptr, 1024, 1024, 1024,
      nullptr, nullptr, qb, kb, vb);
  // 3) per-head rmsnorm + rotary on q,k
  k_qkrot<<<dim3(16384, 2), 256, 0, stream>>>(qb, kb);
  // 4) causal attention (register-tiled)
  k_attn<<<1024, 256, 0, stream>>>(qb, kb, vb, ob);
  // 5) x2 = x' + o @ c_proj_w^T + b  -> d_out
  k_gemm<1><<<dim3(8, 32), 256, 0, stream>>>(ob, c_proj_w, out, 1024, 1024, 1024,
      c_proj_b, xr, nullptr, nullptr, nullptr);
  // 6) h = rmsnorm(x2)
  k_norm<<<NTOK, 256, 0, stream>>>(out, nullptr, nullptr, nullptr, h);
  // 7) router decisions
  k_router<<<NTOK, 256, 0, stream>>>(h, router_w, router_b, noise_w, noise_b,
                                     noise, eid, gate0);
  // 8) ordered compaction into per-expert slot lists
  k_assign<<<1, 256, 0, stream>>>(eid, slots, counts);

  // 9) expert FFNs in bf16 MFMA
  float* exbase = ws + OFF_A;
  unsigned short* h_b = (unsigned short*)exbase;
  float* chunkbase = exbase + 2097152;
  const size_t ws_floats = ws_size / 4;
  long avail = (long)ws_floats - (long)(OFF_A + 2097152);
  int chunk = (int)(avail / (3L * 2097152));
  if (chunk < 1) chunk = 1;
  if (chunk > E_) chunk = E_;

  k_cast<<<2048, 256, 0, stream>>>(h, h_b, 1048576);

  for (int eb = 0; eb < E_; eb += chunk) {
    const int ce = (E_ - eb < chunk) ? (E_ - eb) : chunk;
    unsigned short* ew1b = (unsigned short*)chunkbase;
    unsigned short* ew2b = (unsigned short*)(chunkbase + (size_t)chunk * 2097152);
    unsigned short* h1b  = (unsigned short*)(chunkbase + (size_t)2 * chunk * 2097152);
    k_cast<<<2048, 256, 0, stream>>>(ew1 + (size_t)eb * 4194304, ew1b, ce * 1048576);
    k_cast<<<2048, 256, 0, stream>>>(ew2 + (size_t)eb * 4194304, ew2b, ce * 1048576);
    k_mgemm<0><<<dim3(32, 8, ce), 256, 0, stream>>>(h_b, ew1b, 1024, 1024, 1024,
        eb1, h1b, nullptr, slots, counts, nullptr, eb);
    k_mgemm<1><<<dim3(8, 8, ce), 256, 0, stream>>>(h1b, ew2b, 4096, 4096, 4096,
        eb2, nullptr, out, slots, counts, gate0, eb);
  }
}

// Round 9
// 4852.702 us; speedup vs baseline: 1.1004x; 1.1004x over previous
//
#include <hip/hip_runtime.h>
#include <math.h>

#define B_    2
#define T_    2048
#define C_    1024
#define H_    16
#define HD_   64
#define E_    8
#define NTOK  4096
#define CAP_  1024
#define FOURC 4096
#define EPS_  1e-6f

typedef __attribute__((ext_vector_type(8))) short bf16x8;
typedef __attribute__((ext_vector_type(4))) float f32x4;

// ---------------- workspace layout (float offsets) ----------------
#define OFF_XR   ((size_t)0)                    // 4194304 : x' = l0*x + l1*x0
#define OFF_H    ((size_t)4194304)              // 4194304 : h = rmsnorm(x2)
#define OFF_MISC ((size_t)8388608)              // 32768   : eid/g0/slots/counts
#define OFF_A    (OFF_MISC + 32768)             // attention scratch, dead by expert phase
#define OFF_O    (OFF_A + 4194304)
#define OFF_Q    (OFF_O + 4194304)
#define OFF_K    (OFF_Q + 4194304)
#define OFF_V    (OFF_K + 4194304)
// expert phase overlays OFF_A.. : h_bf16 (2M floats) + chunk{ew1b,ew2b,h1b}

__device__ __forceinline__ float4 ld4(const float* p) { return *(const float4*)p; }

__device__ __forceinline__ unsigned short f2b(float x) {  // fp32 -> bf16 RNE
  unsigned int u = __float_as_uint(x);
  u = (u + 0x7FFFu + ((u >> 16) & 1u)) >> 16;
  return (unsigned short)u;
}

// ---------------- fused (optional mix) + rmsnorm ----------------
__global__ __launch_bounds__(256)
void k_norm(const float* __restrict__ in, const float* __restrict__ in2,
            const float* __restrict__ lambdas,
            float* __restrict__ rawOut, float* __restrict__ normOut) {
  const int row = blockIdx.x;
  const int t = threadIdx.x;
  const size_t base = (size_t)row * C_ + t * 4;
  float4 v = ld4(in + base);
  float4 m;
  if (in2 != nullptr) {
    const float l0 = lambdas[0], l1 = lambdas[1];
    float4 v2 = ld4(in2 + base);
    m.x = l0 * v.x + l1 * v2.x;
    m.y = l0 * v.y + l1 * v2.y;
    m.z = l0 * v.z + l1 * v2.z;
    m.w = l0 * v.w + l1 * v2.w;
  } else {
    m = v;
  }
  float ss = m.x * m.x + m.y * m.y + m.z * m.z + m.w * m.w;
  #pragma unroll
  for (int off = 32; off > 0; off >>= 1) ss += __shfl_xor(ss, off);
  __shared__ float red[4];
  if ((t & 63) == 0) red[t >> 6] = ss;
  __syncthreads();
  const float tot = red[0] + red[1] + red[2] + red[3];
  const float inv = 1.0f / sqrtf(tot * (1.0f / C_) + EPS_);
  if (rawOut != nullptr) *(float4*)(rawOut + base) = m;
  float4 nm;
  nm.x = m.x * inv; nm.y = m.y * inv; nm.z = m.z * inv; nm.w = m.w * inv;
  *(float4*)(normOut + base) = nm;
}

// ---------------- fp32 NT-GEMM (qkv / c_proj only) ----------------
#define BM 128
#define BN 128
#define BK 16
#define PA 132

template<int MODE>   // 0: qkv scatter, 1: c_proj + bias + resid
__global__ __launch_bounds__(256, 2)
void k_gemm(const float* __restrict__ Ag, const float* __restrict__ Bg,
            float* __restrict__ Cg, int Kd, int lda, int ldb,
            const float* __restrict__ bias, const float* __restrict__ resid,
            float* __restrict__ oq, float* __restrict__ ok, float* __restrict__ ov) {
  __shared__ float As[BK * PA];
  __shared__ float Bs[BK * PA];

  const int tid = threadIdx.x;
  const int n0 = blockIdx.x * BN;
  const int m0 = blockIdx.y * BM;

  const int r = tid >> 2;            // 0..63
  const int f4 = (tid & 3) * 4;      // 0,4,8,12

  const float* pa0 = Ag + (size_t)(m0 + r) * lda + f4;
  const float* pa1 = Ag + (size_t)(m0 + r + 64) * lda + f4;
  const float* pb0 = Bg + (size_t)(n0 + r) * ldb + f4;
  const float* pb1 = Bg + (size_t)(n0 + r + 64) * ldb + f4;

  float4 ga0, ga1, gb0, gb1;
  const int nkt = Kd >> 4;

  ga0 = ld4(pa0); ga1 = ld4(pa1); gb0 = ld4(pb0); gb1 = ld4(pb1);

  const int tx = tid & 15, ty = tid >> 4;
  float acc[8][8];
  #pragma unroll
  for (int i = 0; i < 8; i++)
    #pragma unroll
    for (int j = 0; j < 8; j++) acc[i][j] = 0.f;

  for (int kt = 0; kt < nkt; kt++) {
    __syncthreads();
    #pragma unroll
    for (int l = 0; l < 4; l++) {
      As[(f4 + l) * PA + r]      = (&ga0.x)[l];
      As[(f4 + l) * PA + r + 64] = (&ga1.x)[l];
      Bs[(f4 + l) * PA + r]      = (&gb0.x)[l];
      Bs[(f4 + l) * PA + r + 64] = (&gb1.x)[l];
    }
    __syncthreads();
    if (kt + 1 < nkt) {
      const int k0 = (kt + 1) * BK;
      ga0 = ld4(pa0 + k0); ga1 = ld4(pa1 + k0);
      gb0 = ld4(pb0 + k0); gb1 = ld4(pb1 + k0);
    }
    #pragma unroll
    for (int kk = 0; kk < BK; kk++) {
      float4 a0 = *(float4*)&As[kk * PA + ty * 4];
      float4 a1 = *(float4*)&As[kk * PA + ty * 4 + 64];
      float4 b0 = *(float4*)&Bs[kk * PA + tx * 4];
      float4 b1 = *(float4*)&Bs[kk * PA + tx * 4 + 64];
      float av[8] = {a0.x, a0.y, a0.z, a0.w, a1.x, a1.y, a1.z, a1.w};
      float bv[8] = {b0.x, b0.y, b0.z, b0.w, b1.x, b1.y, b1.z, b1.w};
      #pragma unroll
      for (int i = 0; i < 8; i++)
        #pragma unroll
        for (int j = 0; j < 8; j++) acc[i][j] += av[i] * bv[j];
    }
  }

  #pragma unroll
  for (int ih = 0; ih < 2; ih++) {
    #pragma unroll
    for (int ii = 0; ii < 4; ii++) {
      const int i = ih * 4 + ii;
      const int m = m0 + ty * 4 + ii + ih * 64;
      #pragma unroll
      for (int jh = 0; jh < 2; jh++) {
        const int n = n0 + tx * 4 + jh * 64;
        float4 vv = make_float4(acc[i][jh * 4 + 0], acc[i][jh * 4 + 1],
                                acc[i][jh * 4 + 2], acc[i][jh * 4 + 3]);
        if (MODE == 0) {
          const int kap = n >> 10;
          const int hh = (n >> 6) & 15;
          const int d = n & 63;
          const int bq = m >> 11, tq = m & 2047;
          float* dst = (kap == 0) ? oq : ((kap == 1) ? ok : ov);
          *(float4*)(dst + ((size_t)((bq * 16 + hh) * 2048 + tq)) * 64 + d) = vv;
        } else {
          float4 bb = ld4(bias + n);
          float4 rr = ld4(resid + (size_t)m * C_ + n);
          vv.x += bb.x + rr.x; vv.y += bb.y + rr.y;
          vv.z += bb.z + rr.z; vv.w += bb.w + rr.w;
          *(float4*)(Cg + (size_t)m * C_ + n) = vv;
        }
      }
    }
  }
}

// ---------------- q/k rmsnorm + rotary ----------------
__global__ __launch_bounds__(256)
void k_qkrot(float* __restrict__ qb, float* __restrict__ kb) {
  const int w = threadIdx.x >> 6, lane = threadIdx.x & 63;
  const int row = blockIdx.x * 4 + w;
  float* buf = (blockIdx.y == 0) ? qb : kb;
  const int t = row & 2047;
  float val = buf[(size_t)row * 64 + lane];
  float ss = val * val;
  #pragma unroll
  for (int off = 32; off > 0; off >>= 1) ss += __shfl_xor(ss, off);
  const float nrm = val / sqrtf(ss * (1.0f / 64.0f) + EPS_);
  const int i = lane & 31;
  float c, s;
  if (i < 16) {
    const float y = (float)i * (1.0f / 15.0f);
    const float inv = exp2f(-10.0f * y);           // (1/1024)^y
    const float ang = (float)t * inv;
    c = cosf(ang); s = sinf(ang);
  } else { c = 1.0f; s = 0.0f; }
  const float partner = __shfl_xor(nrm, 32);
  const float out = (lane < 32) ? (nrm * c + partner * s) : (partner * (-s) + nrm * c);
  buf[(size_t)row * 64 + lane] = out;
}

// ---------------- causal flash attention, fp32, 4x4 register tiles ----------------
// 256 thr = 4 waves; wave owns 16 rows; per-lane 4x4 micro-tile.
// Fixed-max softmax (|s|<=8 exact): p = exp(s-8), denominators deferred.
// NOTE: no address-of into register float4 ARRAYS anywhere (kpf/vpf) -- that
// pattern defeated SROA in round 5 and demoted the arrays to scratch
// (WRITE_SIZE 8.9GB/dispatch). Component access (.x/.y/.z/.w) only.
// Grid: gid = inner*8 + xcd, xcd = bh&7 -> each XCD's L2 holds its 4 heads' K/V.
__global__ __launch_bounds__(256, 2)
void k_attn(const float* __restrict__ q, const float* __restrict__ k,
            const float* __restrict__ v, float* __restrict__ o) {
  const int gid = blockIdx.x;          // 0..1023
  const int xcd = gid & 7;
  const int inner = gid >> 3;          // 0..127
  const int rg = 31 - (inner >> 2);    // heavy blocks first within each XCD
  const int bh = ((inner & 3) << 3) | xcd;
  const int tid = threadIdx.x;
  const int w = tid >> 6, lane = tid & 63;
  const int rq = lane >> 4;            // row quad within wave's 16 rows
  const int cq = lane & 15;            // key-quad (scores) / dim-quad (PV)
  __shared__ float qs[64 * 64];
  __shared__ float Ks[64 * 64];
  __shared__ float Vt[64 * 64];        // Vt[d][j]
  __shared__ float ps[64 * 64];
  const size_t base = (size_t)bh * (T_ * HD_);
  const int row0 = rg * 64;

  {  // stage q (pre-scaled by 1/sqrt(HD)), swizzled
    const int c = tid & 15;
    #pragma unroll
    for (int p = 0; p < 4; p++) {
      const int r = p * 16 + (tid >> 4);
      float4 qv = ld4(q + base + (size_t)(row0 + r) * 64 + c * 4);
      qv.x *= 0.125f; qv.y *= 0.125f; qv.z *= 0.125f; qv.w *= 0.125f;
      *(float4*)&qs[r * 64 + ((c ^ ((r >> 2) & 7)) << 2)] = qv;
    }
  }

  float oacc[4][4];
  float lsum[4];
  #pragma unroll
  for (int i = 0; i < 4; i++) {
    lsum[i] = 0.f;
    #pragma unroll
    for (int j = 0; j < 4; j++) oacc[i][j] = 0.f;
  }

  const int swzR = ((w * 4 + rq) & 7);   // row-side swizzle for qs/ps reads
  const int swzC = (cq & 7);             // col-side swizzle for Ks/Vt reads
  const int rbase = w * 16 + rq * 4;     // wave's local row base for this lane

  // tile-0 prefetch into regs (whole-float4 and component access only)
  float4 kpf[4], vpf[4];
  {
    const int c = tid & 15;
    #pragma unroll
    for (int p = 0; p < 4; p++) {
      const int r = p * 16 + (tid >> 4);
      kpf[p] = ld4(k + base + (size_t)r * 64 + c * 4);
      vpf[p] = ld4(v + base + (size_t)r * 64 + c * 4);
    }
  }

  for (int kt = 0; kt <= rg; kt++) {
    const int j0 = kt * 64;
    __syncthreads();   // previous tile fully consumed by all waves
    {  // write staged K / V^T from prefetch regs
      const int c = tid & 15;
      #pragma unroll
      for (int p = 0; p < 4; p++) {
        const int r = p * 16 + (tid >> 4);
        *(float4*)&Ks[r * 64 + ((c ^ ((r >> 2) & 7)) << 2)] = kpf[p];
        // V^T scatter: rows d=4c..4c+3 share swizzled column (d>>2 == c)
        const int vcol = (((r >> 2) ^ (c & 7)) << 2) | (r & 3);
        Vt[(c * 4 + 0) * 64 + vcol] = vpf[p].x;
        Vt[(c * 4 + 1) * 64 + vcol] = vpf[p].y;
        Vt[(c * 4 + 2) * 64 + vcol] = vpf[p].z;
        Vt[(c * 4 + 3) * 64 + vcol] = vpf[p].w;
      }
    }
    __syncthreads();
    if (kt < rg) {  // issue next tile's loads early (land under compute)
      const int c = tid & 15;
      #pragma unroll
      for (int p = 0; p < 4; p++) {
        const int r = p * 16 + (tid >> 4);
        kpf[p] = ld4(k + base + (size_t)(j0 + 64 + r) * 64 + c * 4);
        vpf[p] = ld4(v + base + (size_t)(j0 + 64 + r) * 64 + c * 4);
      }
    }

    // ---- scores: S[rbase..+3][cq*4..+3] ----
    float acc[4][4];
    #pragma unroll
    for (int i = 0; i < 4; i++)
      #pragma unroll
      for (int j = 0; j < 4; j++) acc[i][j] = 0.f;

    #pragma unroll
    for (int d4 = 0; d4 < 16; d4++) {
      float4 kk[4], qq[4];
      #pragma unroll
      for (int i = 0; i < 4; i++) {
        kk[i] = *(float4*)&Ks[(cq * 4 + i) * 64 + ((d4 ^ swzC) << 2)];
        qq[i] = *(float4*)&qs[(rbase + i) * 64 + ((d4 ^ swzR) << 2)];
      }
      #pragma unroll
      for (int ri = 0; ri < 4; ri++)
        #pragma unroll
        for (int ji = 0; ji < 4; ji++) {
          acc[ri][ji] += qq[ri].x * kk[ji].x + qq[ri].y * kk[ji].y
                       + qq[ri].z * kk[ji].z + qq[ri].w * kk[ji].w;
        }
    }

    // ---- masked exp, partial row sums, write P (component-explicit) ----
    #pragma unroll
    for (int ri = 0; ri < 4; ri++) {
      const int r = row0 + rbase + ri;
      float4 pv;
      pv.x = (j0 + cq * 4 + 0 <= r) ? __expf(acc[ri][0] - 8.0f) : 0.f;
      pv.y = (j0 + cq * 4 + 1 <= r) ? __expf(acc[ri][1] - 8.0f) : 0.f;
      pv.z = (j0 + cq * 4 + 2 <= r) ? __expf(acc[ri][2] - 8.0f) : 0.f;
      pv.w = (j0 + cq * 4 + 3 <= r) ? __expf(acc[ri][3] - 8.0f) : 0.f;
      lsum[ri] += pv.x + pv.y + pv.z + pv.w;
      *(float4*)&ps[(rbase + ri) * 64 + ((cq ^ swzR) << 2)] = pv;
    }
    // ps is written and read by the SAME wave only -> no barrier

    // ---- PV: O[rbase..+3][cq*4..+3] += P[rows][j] * V[j][dims] ----
    #pragma unroll
    for (int jc = 0; jc < 16; jc++) {
      float4 pp[4], vv[4];
      #pragma unroll
      for (int i = 0; i < 4; i++) {
        pp[i] = *(float4*)&ps[(rbase + i) * 64 + ((jc ^ swzR) << 2)];
        vv[i] = *(float4*)&Vt[(cq * 4 + i) * 64 + ((jc ^ swzC) << 2)];
      }
      #pragma unroll
      for (int ri = 0; ri < 4; ri++)
        #pragma unroll
        for (int di = 0; di < 4; di++) {
          oacc[ri][di] += pp[ri].x * vv[di].x + pp[ri].y * vv[di].y
                        + pp[ri].z * vv[di].z + pp[ri].w * vv[di].w;
        }
    }
  }

  // reduce row sums across the 16 lanes sharing rq (lane bits 0..3)
  #pragma unroll
  for (int ri = 0; ri < 4; ri++) {
    float t2 = lsum[ri];
    #pragma unroll
    for (int off = 1; off < 16; off <<= 1) t2 += __shfl_xor(t2, off);
    lsum[ri] = t2;
  }

  const int b = bh >> 4, hh = bh & 15;
  #pragma unroll
  for (int ri = 0; ri < 4; ri++) {
    const int r = row0 + rbase + ri;
    const float inv = 1.0f / lsum[ri];
    float4 ov = make_float4(oacc[ri][0] * inv, oacc[ri][1] * inv,
                            oacc[ri][2] * inv, oacc[ri][3] * inv);
    *(float4*)(o + ((size_t)(b * 2048 + r)) * 1024 + hh * 64 + cq * 4) = ov;
  }
}

// ---------------- router ----------------
__global__ __launch_bounds__(256)
void k_router(const float* __restrict__ h, const float* __restrict__ rw,
              const float* __restrict__ rb, const float* __restrict__ nw,
              const float* __restrict__ nb, const float* __restrict__ noise,
              int* __restrict__ eid, float* __restrict__ gate0) {
  const int m = blockIdx.x;
  const int t = threadIdx.x;
  const float4 hv = ld4(h + (size_t)m * C_ + t * 4);
  float pl[E_], pn[E_];
  #pragma unroll
  for (int e2 = 0; e2 < E_; e2++) {
    float4 wv = ld4(rw + (size_t)e2 * C_ + t * 4);
    pl[e2] = hv.x * wv.x + hv.y * wv.y + hv.z * wv.z + hv.w * wv.w;
    float4 nv = ld4(nw + (size_t)e2 * C_ + t * 4);
    pn[e2] = hv.x * nv.x + hv.y * nv.y + hv.z * nv.z + hv.w * nv.w;
  }
  __shared__ float red[16][4];
  const int w = t >> 6, lane = t & 63;
  #pragma unroll
  for (int idx = 0; idx < 16; idx++) {
    float val = (idx < 8) ? pl[idx] : pn[idx - 8];
    #pragma unroll
    for (int off = 32; off > 0; off >>= 1) val += __shfl_xor(val, off);
    if (lane == 0) red[idx][w] = val;
  }
  __syncthreads();
  if (t == 0) {
    float noisy[E_];
    #pragma unroll
    for (int e2 = 0; e2 < E_; e2++) {
      const float lg = red[e2][0] + red[e2][1] + red[e2][2] + red[e2][3] + rb[e2];
      const float nl = red[8 + e2][0] + red[8 + e2][1] + red[8 + e2][2] + red[8 + e2][3] + nb[e2];
      const float sp = fmaxf(nl, 0.f) + log1pf(expf(-fabsf(nl)));
      noisy[e2] = lg + noise[m * E_ + e2] * sp;
    }
    int i0 = 0; float v0 = noisy[0];
    #pragma unroll
    for (int e2 = 1; e2 < E_; e2++)
      if (noisy[e2] > v0) { v0 = noisy[e2]; i0 = e2; }
    float v1 = -INFINITY;
    #pragma unroll
    for (int e2 = 0; e2 < E_; e2++)
      if (e2 != i0 && noisy[e2] > v1) { v1 = noisy[e2]; }
    eid[m] = i0;
    gate0[m] = 1.0f / (1.0f + expf(v1 - v0));
  }
}

// ---------------- ordered per-expert compaction ----------------
__global__ __launch_bounds__(256)
void k_assign(const int* __restrict__ eid, int* __restrict__ slots,
              int* __restrict__ counts) {
  const int t = threadIdx.x;
  int myeid[16];
  #pragma unroll
  for (int i = 0; i < 16; i++) myeid[i] = eid[t * 16 + i];
  int cnt[E_];
  #pragma unroll
  for (int e2 = 0; e2 < E_; e2++) {
    int c = 0;
    #pragma unroll
    for (int i = 0; i < 16; i++) c += (myeid[i] == e2) ? 1 : 0;
    cnt[e2] = c;
  }
  __shared__ int sc[256];
  #pragma unroll
  for (int e2 = 0; e2 < E_; e2++) {
    sc[t] = cnt[e2];
    __syncthreads();
    for (int off = 1; off < 256; off <<= 1) {
      int xv = (t >= off) ? sc[t - off] : 0;
      __syncthreads();
      sc[t] += xv;
      __syncthreads();
    }
    int rank = sc[t] - cnt[e2];
    if (t == 255) counts[e2] = sc[255];
    #pragma unroll
    for (int i = 0; i < 16; i++) {
      if (myeid[i] == e2) {
        if (rank < CAP_) slots[e2 * CAP_ + rank] = t * 16 + i;
        rank++;
      }
    }
    __syncthreads();
  }
}

// ---------------- fp32 -> bf16 cast (grid-stride over float4) ----------------
__global__ __launch_bounds__(256)
void k_cast(const float* __restrict__ in, unsigned short* __restrict__ outp, int n4) {
  for (int i = blockIdx.x * 256 + threadIdx.x; i < n4; i += gridDim.x * 256) {
    float4 vv = ld4(in + (size_t)i * 4);
    ushort4 u;
    u.x = f2b(vv.x); u.y = f2b(vv.y); u.z = f2b(vv.z); u.w = f2b(vv.w);
    *(ushort4*)(outp + (size_t)i * 4) = u;
  }
}

// ---------------- bf16 MFMA NT-GEMM for experts ----------------
template<int MODE>
__global__ __launch_bounds__(256, 4)
void k_mgemm(const unsigned short* __restrict__ Ab, const unsigned short* __restrict__ Bb,
             int Kd, int lda, int ldb,
             const float* __restrict__ bias,
             unsigned short* __restrict__ h1out, float* __restrict__ fout,
             const int* __restrict__ slots, const int* __restrict__ counts,
             const float* __restrict__ gate, int e0) {
  const int z = blockIdx.z, e = e0 + z;
  int Ne = counts[e]; if (Ne > CAP_) Ne = CAP_;
  const int m0 = blockIdx.y * 128, n0 = blockIdx.x * 128;
  if (m0 >= Ne) return;

  __shared__ __align__(16) unsigned short Asb[128 * 64];
  __shared__ __align__(16) unsigned short Bsb[128 * 64];

  const int tid = threadIdx.x, w = tid >> 6, lane = tid & 63;
  const unsigned short* Az = (MODE == 0) ? Ab : Ab + (size_t)z * CAP_ * FOURC;
  const unsigned short* Bz = Bb + (size_t)z * ((MODE == 0) ? (size_t)FOURC * C_ : (size_t)C_ * FOURC);
  const float* biasz = bias + (size_t)e * ((MODE == 0) ? FOURC : C_);

  const int rsub = lane >> 3;        // 0..7
  const int kc   = lane & 7;         // 0..7 (16B chunk)
  const int sstore = (kc ^ rsub) * 8;

  int arow[4];
  #pragma unroll
  for (int i = 0; i < 4; i++) {
    const int m = m0 + w * 32 + i * 8 + rsub;
    if (MODE == 0) arow[i] = (m < Ne) ? slots[(size_t)e * CAP_ + m] : 0;
    else           arow[i] = m;
  }

  f32x4 acc[4][4];
  #pragma unroll
  for (int mi = 0; mi < 4; mi++)
    #pragma unroll
    for (int ni = 0; ni < 4; ni++) {
      f32x4 zz = {0.f, 0.f, 0.f, 0.f};
      acc[mi][ni] = zz;
    }

  const int wr = (w >> 1) * 64, wc = (w & 1) * 64;
  const int fr = lane & 15, fq = lane >> 4;
  const int nkt = Kd >> 6;

  for (int kt = 0; kt < nkt; kt++) {
    const int kb = kt * 64;
    bf16x8 ga[4], gb[4];
    #pragma unroll
    for (int i = 0; i < 4; i++) {
      ga[i] = *(const bf16x8*)(Az + (size_t)arow[i] * lda + kb + kc * 8);
      gb[i] = *(const bf16x8*)(Bz + (size_t)(n0 + w * 32 + i * 8 + rsub) * ldb + kb + kc * 8);
    }
    __syncthreads();
    #pragma unroll
    for (int i = 0; i < 4; i++) {
      const int rowL = w * 32 + i * 8 + rsub;
      *(bf16x8*)&Asb[rowL * 64 + sstore] = ga[i];
      *(bf16x8*)&Bsb[rowL * 64 + sstore] = gb[i];
    }
    __syncthreads();
    #pragma unroll
    for (int kk = 0; kk < 2; kk++) {
      const int kcl = kk * 4 + fq;
      bf16x8 af[4], bfr[4];
      #pragma unroll
      for (int t2 = 0; t2 < 4; t2++) {
        const int rowA = wr + t2 * 16 + fr;
        af[t2]  = *(const bf16x8*)&Asb[rowA * 64 + ((kcl ^ (rowA & 7)) << 3)];
        const int rowB = wc + t2 * 16 + fr;
        bfr[t2] = *(const bf16x8*)&Bsb[rowB * 64 + ((kcl ^ (rowB & 7)) << 3)];
      }
      #pragma unroll
      for (int mi = 0; mi < 4; mi++)
        #pragma unroll
        for (int ni = 0; ni < 4; ni++)
          acc[mi][ni] = __builtin_amdgcn_mfma_f32_16x16x32_bf16(af[mi], bfr[ni], acc[mi][ni], 0, 0, 0);
    }
  }

  #pragma unroll
  for (int mi = 0; mi < 4; mi++) {
    #pragma unroll
    for (int reg = 0; reg < 4; reg++) {
      const int m = m0 + wr + mi * 16 + fq * 4 + reg;
      if (MODE == 0) {
        #pragma unroll
        for (int ni = 0; ni < 4; ni++) {
          const int n = n0 + wc + ni * 16 + fr;
          const float r = fmaxf(acc[mi][ni][reg] + biasz[n], 0.f);
          h1out[(size_t)z * CAP_ * FOURC + (size_t)m * FOURC + n] = f2b(r * r);
        }
      } else {
        const int tok = (m < Ne) ? slots[(size_t)e * CAP_ + m] : -1;
        if (tok >= 0) {
          const float gg = gate[tok];
          #pragma unroll
          for (int ni = 0; ni < 4; ni++) {
            const int n = n0 + wc + ni * 16 + fr;
            fout[(size_t)tok * C_ + n] += (acc[mi][ni][reg] + biasz[n]) * gg;
          }
        }
      }
    }
  }
}

// ---------------- launcher ----------------
extern "C" void kernel_launch(void* const* d_in, const int* in_sizes, int n_in,
                              void* d_out, int out_size, void* d_ws, size_t ws_size,
                              hipStream_t stream) {
  const float* x        = (const float*)d_in[0];
  const float* x0       = (const float*)d_in[1];
  const float* noise    = (const float*)d_in[2];
  const float* lambdas  = (const float*)d_in[3];
  // d_in[4] = lamb: (1-lamb)*v + lamb*v == v -> unused
  const float* qkv_w    = (const float*)d_in[5];
  const float* c_proj_w = (const float*)d_in[6];
  const float* c_proj_b = (const float*)d_in[7];
  const float* router_w = (const float*)d_in[8];
  const float* router_b = (const float*)d_in[9];
  const float* noise_w  = (const float*)d_in[10];
  const float* noise_b  = (const float*)d_in[11];
  const float* ew1      = (const float*)d_in[12];
  const float* eb1      = (const float*)d_in[13];
  const float* ew2      = (const float*)d_in[14];
  const float* eb2      = (const float*)d_in[15];
  float* out = (float*)d_out;
  float* ws  = (float*)d_ws;

  float* xr  = ws + OFF_XR;
  float* h   = ws + OFF_H;
  int*   eid    = (int*)(ws + OFF_MISC);
  float* gate0  = ws + OFF_MISC + 4096;
  int*   slots  = (int*)(ws + OFF_MISC + 8192);
  int*   counts = (int*)(ws + OFF_MISC + 16384);
  float* a   = ws + OFF_A;
  float* ob  = ws + OFF_O;
  float* qb  = ws + OFF_Q;
  float* kb  = ws + OFF_K;
  float* vb  = ws + OFF_V;

  // 1) x' = l0*x + l1*x0 ; a = rmsnorm(x')
  k_norm<<<NTOK, 256, 0, stream>>>(x, x0, lambdas, xr, a);
  // 2) qkv = a @ qkv_w^T, scattered into head layout
  k_gemm<0><<<dim3(24, 32), 256, 0, stream>>>(a, qkv_w, nullptr, 1024, 1024, 1024,
      nullptr, nullptr, qb, kb, vb);
  // 3) per-head rmsnorm + rotary on q,k
  k_qkrot<<<dim3(16384, 2), 256, 0, stream>>>(qb, kb);
  // 4) causal attention (register-tiled, scratch-free)
  k_attn<<<1024, 256, 0, stream>>>(qb, kb, vb, ob);
  // 5) x2 = x' + o @ c_proj_w^T + b  -> d_out
  k_gemm<1><<<dim3(8, 32), 256, 0, stream>>>(ob, c_proj_w, out, 1024, 1024, 1024,
      c_proj_b, xr, nullptr, nullptr, nullptr);
  // 6) h = rmsnorm(x2)
  k_norm<<<NTOK, 256, 0, stream>>>(out, nullptr, nullptr, nullptr, h);
  // 7) router decisions
  k_router<<<NTOK, 256, 0, stream>>>(h, router_w, router_b, noise_w, noise_b,
                                     noise, eid, gate0);
  // 8) ordered compaction into per-expert slot lists
  k_assign<<<1, 256, 0, stream>>>(eid, slots, counts);

  // 9) expert FFNs in bf16 MFMA
  float* exbase = ws + OFF_A;
  unsigned short* h_b = (unsigned short*)exbase;
  float* chunkbase = exbase + 2097152;
  const size_t ws_floats = ws_size / 4;
  long avail = (long)ws_floats - (long)(OFF_A + 2097152);
  int chunk = (int)(avail / (3L * 2097152));
  if (chunk < 1) chunk = 1;
  if (chunk > E_) chunk = E_;

  k_cast<<<2048, 256, 0, stream>>>(h, h_b, 1048576);

  for (int eb = 0; eb < E_; eb += chunk) {
    const int ce = (E_ - eb < chunk) ? (E_ - eb) : chunk;
    unsigned short* ew1b = (unsigned short*)chunkbase;
    unsigned short* ew2b = (unsigned short*)(chunkbase + (size_t)chunk * 2097152);
    unsigned short* h1b  = (unsigned short*)(chunkbase + (size_t)2 * chunk * 2097152);
    k_cast<<<2048, 256, 0, stream>>>(ew1 + (size_t)eb * 4194304, ew1b, ce * 1048576);
    k_cast<<<2048, 256, 0, stream>>>(ew2 + (size_t)eb * 4194304, ew2b, ce * 1048576);
    k_mgemm<0><<<dim3(32, 8, ce), 256, 0, stream>>>(h_b, ew1b, 1024, 1024, 1024,
        eb1, h1b, nullptr, slots, counts, nullptr, eb);
    k_mgemm<1><<<dim3(8, 8, ce), 256, 0, stream>>>(h1b, ew2b, 4096, 4096, 4096,
        eb2, nullptr, out, slots, counts, gate0, eb);
  }
}

// Round 10
// 1893.698 us; speedup vs baseline: 2.8198x; 2.5626x over previous
//
#include <hip/hip_runtime.h>
#include <math.h>

#define B_    2
#define T_    2048
#define C_    1024
#define H_    16
#define HD_   64
#define E_    8
#define NTOK  4096
#define CAP_  1024
#define FOURC 4096
#define EPS_  1e-6f

typedef __attribute__((ext_vector_type(8))) short bf16x8;
typedef __attribute__((ext_vector_type(4))) float f32x4;

// ---------------- workspace layout (float offsets) ----------------
#define OFF_XR   ((size_t)0)
#define OFF_H    ((size_t)4194304)
#define OFF_MISC ((size_t)8388608)
#define OFF_A    (OFF_MISC + 32768)
#define OFF_O    (OFF_A + 4194304)
#define OFF_Q    (OFF_O + 4194304)
#define OFF_K    (OFF_Q + 4194304)
#define OFF_V    (OFF_K + 4194304)

__device__ __forceinline__ float4 ld4(const float* p) { return *(const float4*)p; }

__device__ __forceinline__ unsigned short f2b(float x) {  // fp32 -> bf16 RNE
  unsigned int u = __float_as_uint(x);
  u = (u + 0x7FFFu + ((u >> 16) & 1u)) >> 16;
  return (unsigned short)u;
}

// ---------------- fused (optional mix) + rmsnorm ----------------
__global__ __launch_bounds__(256)
void k_norm(const float* __restrict__ in, const float* __restrict__ in2,
            const float* __restrict__ lambdas,
            float* __restrict__ rawOut, float* __restrict__ normOut) {
  const int row = blockIdx.x;
  const int t = threadIdx.x;
  const size_t base = (size_t)row * C_ + t * 4;
  float4 v = ld4(in + base);
  float4 m;
  if (in2 != nullptr) {
    const float l0 = lambdas[0], l1 = lambdas[1];
    float4 v2 = ld4(in2 + base);
    m.x = l0 * v.x + l1 * v2.x;
    m.y = l0 * v.y + l1 * v2.y;
    m.z = l0 * v.z + l1 * v2.z;
    m.w = l0 * v.w + l1 * v2.w;
  } else {
    m = v;
  }
  float ss = m.x * m.x + m.y * m.y + m.z * m.z + m.w * m.w;
  #pragma unroll
  for (int off = 32; off > 0; off >>= 1) ss += __shfl_xor(ss, off);
  __shared__ float red[4];
  if ((t & 63) == 0) red[t >> 6] = ss;
  __syncthreads();
  const float tot = red[0] + red[1] + red[2] + red[3];
  const float inv = 1.0f / sqrtf(tot * (1.0f / C_) + EPS_);
  if (rawOut != nullptr) *(float4*)(rawOut + base) = m;
  float4 nm;
  nm.x = m.x * inv; nm.y = m.y * inv; nm.z = m.z * inv; nm.w = m.w * inv;
  *(float4*)(normOut + base) = nm;
}

// ---------------- fp32 NT-GEMM (qkv / c_proj only) ----------------
#define BM 128
#define BN 128
#define BK 16
#define PA 132

template<int MODE>   // 0: qkv scatter, 1: c_proj + bias + resid
__global__ __launch_bounds__(256, 2)
void k_gemm(const float* __restrict__ Ag, const float* __restrict__ Bg,
            float* __restrict__ Cg, int Kd, int lda, int ldb,
            const float* __restrict__ bias, const float* __restrict__ resid,
            float* __restrict__ oq, float* __restrict__ ok, float* __restrict__ ov) {
  __shared__ float As[BK * PA];
  __shared__ float Bs[BK * PA];

  const int tid = threadIdx.x;
  const int n0 = blockIdx.x * BN;
  const int m0 = blockIdx.y * BM;

  const int r = tid >> 2;            // 0..63
  const int f4 = (tid & 3) * 4;      // 0,4,8,12

  const float* pa0 = Ag + (size_t)(m0 + r) * lda + f4;
  const float* pa1 = Ag + (size_t)(m0 + r + 64) * lda + f4;
  const float* pb0 = Bg + (size_t)(n0 + r) * ldb + f4;
  const float* pb1 = Bg + (size_t)(n0 + r + 64) * ldb + f4;

  float4 ga0, ga1, gb0, gb1;
  const int nkt = Kd >> 4;

  ga0 = ld4(pa0); ga1 = ld4(pa1); gb0 = ld4(pb0); gb1 = ld4(pb1);

  const int tx = tid & 15, ty = tid >> 4;
  float acc[8][8];
  #pragma unroll
  for (int i = 0; i < 8; i++)
    #pragma unroll
    for (int j = 0; j < 8; j++) acc[i][j] = 0.f;

  for (int kt = 0; kt < nkt; kt++) {
    __syncthreads();
    #pragma unroll
    for (int l = 0; l < 4; l++) {
      As[(f4 + l) * PA + r]      = (&ga0.x)[l];
      As[(f4 + l) * PA + r + 64] = (&ga1.x)[l];
      Bs[(f4 + l) * PA + r]      = (&gb0.x)[l];
      Bs[(f4 + l) * PA + r + 64] = (&gb1.x)[l];
    }
    __syncthreads();
    if (kt + 1 < nkt) {
      const int k0 = (kt + 1) * BK;
      ga0 = ld4(pa0 + k0); ga1 = ld4(pa1 + k0);
      gb0 = ld4(pb0 + k0); gb1 = ld4(pb1 + k0);
    }
    #pragma unroll
    for (int kk = 0; kk < BK; kk++) {
      float4 a0 = *(float4*)&As[kk * PA + ty * 4];
      float4 a1 = *(float4*)&As[kk * PA + ty * 4 + 64];
      float4 b0 = *(float4*)&Bs[kk * PA + tx * 4];
      float4 b1 = *(float4*)&Bs[kk * PA + tx * 4 + 64];
      float av[8] = {a0.x, a0.y, a0.z, a0.w, a1.x, a1.y, a1.z, a1.w};
      float bv[8] = {b0.x, b0.y, b0.z, b0.w, b1.x, b1.y, b1.z, b1.w};
      #pragma unroll
      for (int i = 0; i < 8; i++)
        #pragma unroll
        for (int j = 0; j < 8; j++) acc[i][j] += av[i] * bv[j];
    }
  }

  #pragma unroll
  for (int ih = 0; ih < 2; ih++) {
    #pragma unroll
    for (int ii = 0; ii < 4; ii++) {
      const int i = ih * 4 + ii;
      const int m = m0 + ty * 4 + ii + ih * 64;
      #pragma unroll
      for (int jh = 0; jh < 2; jh++) {
        const int n = n0 + tx * 4 + jh * 64;
        float4 vv = make_float4(acc[i][jh * 4 + 0], acc[i][jh * 4 + 1],
                                acc[i][jh * 4 + 2], acc[i][jh * 4 + 3]);
        if (MODE == 0) {
          const int kap = n >> 10;
          const int hh = (n >> 6) & 15;
          const int d = n & 63;
          const int bq = m >> 11, tq = m & 2047;
          float* dst = (kap == 0) ? oq : ((kap == 1) ? ok : ov);
          *(float4*)(dst + ((size_t)((bq * 16 + hh) * 2048 + tq)) * 64 + d) = vv;
        } else {
          float4 bb = ld4(bias + n);
          float4 rr = ld4(resid + (size_t)m * C_ + n);
          vv.x += bb.x + rr.x; vv.y += bb.y + rr.y;
          vv.z += bb.z + rr.z; vv.w += bb.w + rr.w;
          *(float4*)(Cg + (size_t)m * C_ + n) = vv;
        }
      }
    }
  }
}

// ---------------- q/k rmsnorm + rotary ----------------
__global__ __launch_bounds__(256)
void k_qkrot(float* __restrict__ qb, float* __restrict__ kb) {
  const int w = threadIdx.x >> 6, lane = threadIdx.x & 63;
  const int row = blockIdx.x * 4 + w;
  float* buf = (blockIdx.y == 0) ? qb : kb;
  const int t = row & 2047;
  float val = buf[(size_t)row * 64 + lane];
  float ss = val * val;
  #pragma unroll
  for (int off = 32; off > 0; off >>= 1) ss += __shfl_xor(ss, off);
  const float nrm = val / sqrtf(ss * (1.0f / 64.0f) + EPS_);
  const int i = lane & 31;
  float c, s;
  if (i < 16) {
    const float y = (float)i * (1.0f / 15.0f);
    const float inv = exp2f(-10.0f * y);           // (1/1024)^y
    const float ang = (float)t * inv;
    c = cosf(ang); s = sinf(ang);
  } else { c = 1.0f; s = 0.0f; }
  const float partner = __shfl_xor(nrm, 32);
  const float out = (lane < 32) ? (nrm * c + partner * s) : (partner * (-s) + nrm * c);
  buf[(size_t)row * 64 + lane] = out;
}

// ---------------- causal flash attention, fp32, 4x4 register tiles ----------------
// 256 thr = 4 waves; wave owns 16 rows; per-lane 4x4 micro-tile.
// Fixed-max softmax (|s|<=8 exact): p = exp(s-8), denominators deferred.
// SPILL-PROOFING (rounds 5 & 9 post-mortems): NO register float4 ARRAYS at all
// in this kernel -- every temporary is an individually named variable (s00..s33,
// oacc00..oacc33, k0..k3, q0..q3, p0..p3, v0..v3). Indexed float4 arrays inside
// the unrolled loops were scratch-allocated (2.1KB/thread/tile = 9GB WRITE_SIZE).
// Staging is direct global->LDS (round-4-proven, no prefetch arrays).
__global__ __launch_bounds__(256, 2)
void k_attn(const float* __restrict__ q, const float* __restrict__ k,
            const float* __restrict__ v, float* __restrict__ o) {
  const int gid = blockIdx.x;          // 0..1023
  const int xcd = gid & 7;
  const int inner = gid >> 3;          // 0..127
  const int rg = 31 - (inner >> 2);    // heavy blocks first within each XCD
  const int bh = ((inner & 3) << 3) | xcd;
  const int tid = threadIdx.x;
  const int w = tid >> 6, lane = tid & 63;
  const int rq = lane >> 4;            // row quad within wave's 16 rows
  const int cq = lane & 15;            // key-quad (scores) / dim-quad (PV)
  __shared__ float qs[64 * 64];
  __shared__ float Ks[64 * 64];
  __shared__ float Vt[64 * 64];        // Vt[d][j]
  __shared__ float ps[64 * 64];
  const size_t base = (size_t)bh * (T_ * HD_);
  const int row0 = rg * 64;

  {  // stage q (pre-scaled by 1/sqrt(HD)), swizzled
    const int c = tid & 15;
    #pragma unroll
    for (int p = 0; p < 4; p++) {
      const int r = p * 16 + (tid >> 4);
      float4 qv = ld4(q + base + (size_t)(row0 + r) * 64 + c * 4);
      qv.x *= 0.125f; qv.y *= 0.125f; qv.z *= 0.125f; qv.w *= 0.125f;
      *(float4*)&qs[r * 64 + ((c ^ ((r >> 2) & 7)) << 2)] = qv;
    }
  }

  float oacc00=0.f, oacc01=0.f, oacc02=0.f, oacc03=0.f;
  float oacc10=0.f, oacc11=0.f, oacc12=0.f, oacc13=0.f;
  float oacc20=0.f, oacc21=0.f, oacc22=0.f, oacc23=0.f;
  float oacc30=0.f, oacc31=0.f, oacc32=0.f, oacc33=0.f;
  float lsum0=0.f, lsum1=0.f, lsum2=0.f, lsum3=0.f;

  const int swzR = ((w * 4 + rq) & 7);   // row-side swizzle for qs/ps reads
  const int swzC = (cq & 7);             // col-side swizzle for Ks/Vt reads
  const int rbase = w * 16 + rq * 4;     // wave's local row base for this lane

  for (int kt = 0; kt <= rg; kt++) {
    const int j0 = kt * 64;
    __syncthreads();   // previous tile fully consumed by all waves
    {  // stage K / V^T directly global->LDS (no persistent register arrays)
      const int c = tid & 15;
      #pragma unroll
      for (int p = 0; p < 4; p++) {
        const int r = p * 16 + (tid >> 4);
        float4 kv = ld4(k + base + (size_t)(j0 + r) * 64 + c * 4);
        *(float4*)&Ks[r * 64 + ((c ^ ((r >> 2) & 7)) << 2)] = kv;
        float4 vv = ld4(v + base + (size_t)(j0 + r) * 64 + c * 4);
        const int vcol = (((r >> 2) ^ (c & 7)) << 2) | (r & 3);
        Vt[(c * 4 + 0) * 64 + vcol] = vv.x;
        Vt[(c * 4 + 1) * 64 + vcol] = vv.y;
        Vt[(c * 4 + 2) * 64 + vcol] = vv.z;
        Vt[(c * 4 + 3) * 64 + vcol] = vv.w;
      }
    }
    __syncthreads();

    // ---- scores: s[ri][ji] = q_(rbase+ri) . k_(cq*4+ji) ----
    float s00=0.f, s01=0.f, s02=0.f, s03=0.f;
    float s10=0.f, s11=0.f, s12=0.f, s13=0.f;
    float s20=0.f, s21=0.f, s22=0.f, s23=0.f;
    float s30=0.f, s31=0.f, s32=0.f, s33=0.f;

    #pragma unroll
    for (int d4 = 0; d4 < 16; d4++) {
      const int ck = (d4 ^ swzC) << 2;
      const int cr = (d4 ^ swzR) << 2;
      const float4 k0 = *(const float4*)&Ks[(cq * 4 + 0) * 64 + ck];
      const float4 k1 = *(const float4*)&Ks[(cq * 4 + 1) * 64 + ck];
      const float4 k2 = *(const float4*)&Ks[(cq * 4 + 2) * 64 + ck];
      const float4 k3 = *(const float4*)&Ks[(cq * 4 + 3) * 64 + ck];
      const float4 q0 = *(const float4*)&qs[(rbase + 0) * 64 + cr];
      const float4 q1 = *(const float4*)&qs[(rbase + 1) * 64 + cr];
      const float4 q2 = *(const float4*)&qs[(rbase + 2) * 64 + cr];
      const float4 q3 = *(const float4*)&qs[(rbase + 3) * 64 + cr];
      s00 += q0.x*k0.x + q0.y*k0.y + q0.z*k0.z + q0.w*k0.w;
      s01 += q0.x*k1.x + q0.y*k1.y + q0.z*k1.z + q0.w*k1.w;
      s02 += q0.x*k2.x + q0.y*k2.y + q0.z*k2.z + q0.w*k2.w;
      s03 += q0.x*k3.x + q0.y*k3.y + q0.z*k3.z + q0.w*k3.w;
      s10 += q1.x*k0.x + q1.y*k0.y + q1.z*k0.z + q1.w*k0.w;
      s11 += q1.x*k1.x + q1.y*k1.y + q1.z*k1.z + q1.w*k1.w;
      s12 += q1.x*k2.x + q1.y*k2.y + q1.z*k2.z + q1.w*k2.w;
      s13 += q1.x*k3.x + q1.y*k3.y + q1.z*k3.z + q1.w*k3.w;
      s20 += q2.x*k0.x + q2.y*k0.y + q2.z*k0.z + q2.w*k0.w;
      s21 += q2.x*k1.x + q2.y*k1.y + q2.z*k1.z + q2.w*k1.w;
      s22 += q2.x*k2.x + q2.y*k2.y + q2.z*k2.z + q2.w*k2.w;
      s23 += q2.x*k3.x + q2.y*k3.y + q2.z*k3.z + q2.w*k3.w;
      s30 += q3.x*k0.x + q3.y*k0.y + q3.z*k0.z + q3.w*k0.w;
      s31 += q3.x*k1.x + q3.y*k1.y + q3.z*k1.z + q3.w*k1.w;
      s32 += q3.x*k2.x + q3.y*k2.y + q3.z*k2.z + q3.w*k2.w;
      s33 += q3.x*k3.x + q3.y*k3.y + q3.z*k3.z + q3.w*k3.w;
    }

    // ---- masked exp, partial row sums, write P ----
    const int jb = j0 + cq * 4;
    const int pscol = (cq ^ swzR) << 2;
    {
      const int r = row0 + rbase + 0;
      float4 pv;
      pv.x = (jb + 0 <= r) ? __expf(s00 - 8.0f) : 0.f;
      pv.y = (jb + 1 <= r) ? __expf(s01 - 8.0f) : 0.f;
      pv.z = (jb + 2 <= r) ? __expf(s02 - 8.0f) : 0.f;
      pv.w = (jb + 3 <= r) ? __expf(s03 - 8.0f) : 0.f;
      lsum0 += pv.x + pv.y + pv.z + pv.w;
      *(float4*)&ps[(rbase + 0) * 64 + pscol] = pv;
    }
    {
      const int r = row0 + rbase + 1;
      float4 pv;
      pv.x = (jb + 0 <= r) ? __expf(s10 - 8.0f) : 0.f;
      pv.y = (jb + 1 <= r) ? __expf(s11 - 8.0f) : 0.f;
      pv.z = (jb + 2 <= r) ? __expf(s12 - 8.0f) : 0.f;
      pv.w = (jb + 3 <= r) ? __expf(s13 - 8.0f) : 0.f;
      lsum1 += pv.x + pv.y + pv.z + pv.w;
      *(float4*)&ps[(rbase + 1) * 64 + pscol] = pv;
    }
    {
      const int r = row0 + rbase + 2;
      float4 pv;
      pv.x = (jb + 0 <= r) ? __expf(s20 - 8.0f) : 0.f;
      pv.y = (jb + 1 <= r) ? __expf(s21 - 8.0f) : 0.f;
      pv.z = (jb + 2 <= r) ? __expf(s22 - 8.0f) : 0.f;
      pv.w = (jb + 3 <= r) ? __expf(s23 - 8.0f) : 0.f;
      lsum2 += pv.x + pv.y + pv.z + pv.w;
      *(float4*)&ps[(rbase + 2) * 64 + pscol] = pv;
    }
    {
      const int r = row0 + rbase + 3;
      float4 pv;
      pv.x = (jb + 0 <= r) ? __expf(s30 - 8.0f) : 0.f;
      pv.y = (jb + 1 <= r) ? __expf(s31 - 8.0f) : 0.f;
      pv.z = (jb + 2 <= r) ? __expf(s32 - 8.0f) : 0.f;
      pv.w = (jb + 3 <= r) ? __expf(s33 - 8.0f) : 0.f;
      lsum3 += pv.x + pv.y + pv.z + pv.w;
      *(float4*)&ps[(rbase + 3) * 64 + pscol] = pv;
    }
    // ps is written and read by the SAME wave only -> no barrier

    // ---- PV: oacc[ri][di] += p_(rbase+ri) . v_(cq*4+di) over this tile ----
    #pragma unroll
    for (int jc = 0; jc < 16; jc++) {
      const int cpp = (jc ^ swzR) << 2;
      const int cvv = (jc ^ swzC) << 2;
      const float4 p0 = *(const float4*)&ps[(rbase + 0) * 64 + cpp];
      const float4 p1 = *(const float4*)&ps[(rbase + 1) * 64 + cpp];
      const float4 p2 = *(const float4*)&ps[(rbase + 2) * 64 + cpp];
      const float4 p3 = *(const float4*)&ps[(rbase + 3) * 64 + cpp];
      const float4 v0 = *(const float4*)&Vt[(cq * 4 + 0) * 64 + cvv];
      const float4 v1 = *(const float4*)&Vt[(cq * 4 + 1) * 64 + cvv];
      const float4 v2 = *(const float4*)&Vt[(cq * 4 + 2) * 64 + cvv];
      const float4 v3 = *(const float4*)&Vt[(cq * 4 + 3) * 64 + cvv];
      oacc00 += p0.x*v0.x + p0.y*v0.y + p0.z*v0.z + p0.w*v0.w;
      oacc01 += p0.x*v1.x + p0.y*v1.y + p0.z*v1.z + p0.w*v1.w;
      oacc02 += p0.x*v2.x + p0.y*v2.y + p0.z*v2.z + p0.w*v2.w;
      oacc03 += p0.x*v3.x + p0.y*v3.y + p0.z*v3.z + p0.w*v3.w;
      oacc10 += p1.x*v0.x + p1.y*v0.y + p1.z*v0.z + p1.w*v0.w;
      oacc11 += p1.x*v1.x + p1.y*v1.y + p1.z*v1.z + p1.w*v1.w;
      oacc12 += p1.x*v2.x + p1.y*v2.y + p1.z*v2.z + p1.w*v2.w;
      oacc13 += p1.x*v3.x + p1.y*v3.y + p1.z*v3.z + p1.w*v3.w;
      oacc20 += p2.x*v0.x + p2.y*v0.y + p2.z*v0.z + p2.w*v0.w;
      oacc21 += p2.x*v1.x + p2.y*v1.y + p2.z*v1.z + p2.w*v1.w;
      oacc22 += p2.x*v2.x + p2.y*v2.y + p2.z*v2.z + p2.w*v2.w;
      oacc23 += p2.x*v3.x + p2.y*v3.y + p2.z*v3.z + p2.w*v3.w;
      oacc30 += p3.x*v0.x + p3.y*v0.y + p3.z*v0.z + p3.w*v0.w;
      oacc31 += p3.x*v1.x + p3.y*v1.y + p3.z*v1.z + p3.w*v1.w;
      oacc32 += p3.x*v2.x + p3.y*v2.y + p3.z*v2.z + p3.w*v2.w;
      oacc33 += p3.x*v3.x + p3.y*v3.y + p3.z*v3.z + p3.w*v3.w;
    }
  }

  // reduce row sums across the 16 lanes sharing rq (lane bits 0..3)
  #pragma unroll
  for (int off = 1; off < 16; off <<= 1) {
    lsum0 += __shfl_xor(lsum0, off);
    lsum1 += __shfl_xor(lsum1, off);
    lsum2 += __shfl_xor(lsum2, off);
    lsum3 += __shfl_xor(lsum3, off);
  }

  const int b = bh >> 4, hh = bh & 15;
  const size_t obase = ((size_t)(b * 2048 + row0 + rbase)) * 1024 + hh * 64 + cq * 4;
  {
    const float inv = 1.0f / lsum0;
    float4 ov = make_float4(oacc00 * inv, oacc01 * inv, oacc02 * inv, oacc03 * inv);
    *(float4*)(o + obase) = ov;
  }
  {
    const float inv = 1.0f / lsum1;
    float4 ov = make_float4(oacc10 * inv, oacc11 * inv, oacc12 * inv, oacc13 * inv);
    *(float4*)(o + obase + 1024) = ov;
  }
  {
    const float inv = 1.0f / lsum2;
    float4 ov = make_float4(oacc20 * inv, oacc21 * inv, oacc22 * inv, oacc23 * inv);
    *(float4*)(o + obase + 2048) = ov;
  }
  {
    const float inv = 1.0f / lsum3;
    float4 ov = make_float4(oacc30 * inv, oacc31 * inv, oacc32 * inv, oacc33 * inv);
    *(float4*)(o + obase + 3072) = ov;
  }
}

// ---------------- router ----------------
__global__ __launch_bounds__(256)
void k_router(const float* __restrict__ h, const float* __restrict__ rw,
              const float* __restrict__ rb, const float* __restrict__ nw,
              const float* __restrict__ nb, const float* __restrict__ noise,
              int* __restrict__ eid, float* __restrict__ gate0) {
  const int m = blockIdx.x;
  const int t = threadIdx.x;
  const float4 hv = ld4(h + (size_t)m * C_ + t * 4);
  float pl[E_], pn[E_];
  #pragma unroll
  for (int e2 = 0; e2 < E_; e2++) {
    float4 wv = ld4(rw + (size_t)e2 * C_ + t * 4);
    pl[e2] = hv.x * wv.x + hv.y * wv.y + hv.z * wv.z + hv.w * wv.w;
    float4 nv = ld4(nw + (size_t)e2 * C_ + t * 4);
    pn[e2] = hv.x * nv.x + hv.y * nv.y + hv.z * nv.z + hv.w * nv.w;
  }
  __shared__ float red[16][4];
  const int w = t >> 6, lane = t & 63;
  #pragma unroll
  for (int idx = 0; idx < 16; idx++) {
    float val = (idx < 8) ? pl[idx] : pn[idx - 8];
    #pragma unroll
    for (int off = 32; off > 0; off >>= 1) val += __shfl_xor(val, off);
    if (lane == 0) red[idx][w] = val;
  }
  __syncthreads();
  if (t == 0) {
    float noisy[E_];
    #pragma unroll
    for (int e2 = 0; e2 < E_; e2++) {
      const float lg = red[e2][0] + red[e2][1] + red[e2][2] + red[e2][3] + rb[e2];
      const float nl = red[8 + e2][0] + red[8 + e2][1] + red[8 + e2][2] + red[8 + e2][3] + nb[e2];
      const float sp = fmaxf(nl, 0.f) + log1pf(expf(-fabsf(nl)));
      noisy[e2] = lg + noise[m * E_ + e2] * sp;
    }
    int i0 = 0; float v0 = noisy[0];
    #pragma unroll
    for (int e2 = 1; e2 < E_; e2++)
      if (noisy[e2] > v0) { v0 = noisy[e2]; i0 = e2; }
    float v1 = -INFINITY;
    #pragma unroll
    for (int e2 = 0; e2 < E_; e2++)
      if (e2 != i0 && noisy[e2] > v1) { v1 = noisy[e2]; }
    eid[m] = i0;
    gate0[m] = 1.0f / (1.0f + expf(v1 - v0));
  }
}

// ---------------- ordered per-expert compaction ----------------
__global__ __launch_bounds__(256)
void k_assign(const int* __restrict__ eid, int* __restrict__ slots,
              int* __restrict__ counts) {
  const int t = threadIdx.x;
  int myeid[16];
  #pragma unroll
  for (int i = 0; i < 16; i++) myeid[i] = eid[t * 16 + i];
  int cnt[E_];
  #pragma unroll
  for (int e2 = 0; e2 < E_; e2++) {
    int c = 0;
    #pragma unroll
    for (int i = 0; i < 16; i++) c += (myeid[i] == e2) ? 1 : 0;
    cnt[e2] = c;
  }
  __shared__ int sc[256];
  #pragma unroll
  for (int e2 = 0; e2 < E_; e2++) {
    sc[t] = cnt[e2];
    __syncthreads();
    for (int off = 1; off < 256; off <<= 1) {
      int xv = (t >= off) ? sc[t - off] : 0;
      __syncthreads();
      sc[t] += xv;
      __syncthreads();
    }
    int rank = sc[t] - cnt[e2];
    if (t == 255) counts[e2] = sc[255];
    #pragma unroll
    for (int i = 0; i < 16; i++) {
      if (myeid[i] == e2) {
        if (rank < CAP_) slots[e2 * CAP_ + rank] = t * 16 + i;
        rank++;
      }
    }
    __syncthreads();
  }
}

// ---------------- fp32 -> bf16 cast (grid-stride over float4) ----------------
__global__ __launch_bounds__(256)
void k_cast(const float* __restrict__ in, unsigned short* __restrict__ outp, int n4) {
  for (int i = blockIdx.x * 256 + threadIdx.x; i < n4; i += gridDim.x * 256) {
    float4 vv = ld4(in + (size_t)i * 4);
    ushort4 u;
    u.x = f2b(vv.x); u.y = f2b(vv.y); u.z = f2b(vv.z); u.w = f2b(vv.w);
    *(ushort4*)(outp + (size_t)i * 4) = u;
  }
}

// ---------------- bf16 MFMA NT-GEMM for experts ----------------
template<int MODE>
__global__ __launch_bounds__(256, 4)
void k_mgemm(const unsigned short* __restrict__ Ab, const unsigned short* __restrict__ Bb,
             int Kd, int lda, int ldb,
             const float* __restrict__ bias,
             unsigned short* __restrict__ h1out, float* __restrict__ fout,
             const int* __restrict__ slots, const int* __restrict__ counts,
             const float* __restrict__ gate, int e0) {
  const int z = blockIdx.z, e = e0 + z;
  int Ne = counts[e]; if (Ne > CAP_) Ne = CAP_;
  const int m0 = blockIdx.y * 128, n0 = blockIdx.x * 128;
  if (m0 >= Ne) return;

  __shared__ __align__(16) unsigned short Asb[128 * 64];
  __shared__ __align__(16) unsigned short Bsb[128 * 64];

  const int tid = threadIdx.x, w = tid >> 6, lane = tid & 63;
  const unsigned short* Az = (MODE == 0) ? Ab : Ab + (size_t)z * CAP_ * FOURC;
  const unsigned short* Bz = Bb + (size_t)z * ((MODE == 0) ? (size_t)FOURC * C_ : (size_t)C_ * FOURC);
  const float* biasz = bias + (size_t)e * ((MODE == 0) ? FOURC : C_);

  const int rsub = lane >> 3;        // 0..7
  const int kc   = lane & 7;         // 0..7 (16B chunk)
  const int sstore = (kc ^ rsub) * 8;

  int arow[4];
  #pragma unroll
  for (int i = 0; i < 4; i++) {
    const int m = m0 + w * 32 + i * 8 + rsub;
    if (MODE == 0) arow[i] = (m < Ne) ? slots[(size_t)e * CAP_ + m] : 0;
    else           arow[i] = m;
  }

  f32x4 acc[4][4];
  #pragma unroll
  for (int mi = 0; mi < 4; mi++)
    #pragma unroll
    for (int ni = 0; ni < 4; ni++) {
      f32x4 zz = {0.f, 0.f, 0.f, 0.f};
      acc[mi][ni] = zz;
    }

  const int wr = (w >> 1) * 64, wc = (w & 1) * 64;
  const int fr = lane & 15, fq = lane >> 4;
  const int nkt = Kd >> 6;

  for (int kt = 0; kt < nkt; kt++) {
    const int kb = kt * 64;
    bf16x8 ga[4], gb[4];
    #pragma unroll
    for (int i = 0; i < 4; i++) {
      ga[i] = *(const bf16x8*)(Az + (size_t)arow[i] * lda + kb + kc * 8);
      gb[i] = *(const bf16x8*)(Bz + (size_t)(n0 + w * 32 + i * 8 + rsub) * ldb + kb + kc * 8);
    }
    __syncthreads();
    #pragma unroll
    for (int i = 0; i < 4; i++) {
      const int rowL = w * 32 + i * 8 + rsub;
      *(bf16x8*)&Asb[rowL * 64 + sstore] = ga[i];
      *(bf16x8*)&Bsb[rowL * 64 + sstore] = gb[i];
    }
    __syncthreads();
    #pragma unroll
    for (int kk = 0; kk < 2; kk++) {
      const int kcl = kk * 4 + fq;
      bf16x8 af[4], bfr[4];
      #pragma unroll
      for (int t2 = 0; t2 < 4; t2++) {
        const int rowA = wr + t2 * 16 + fr;
        af[t2]  = *(const bf16x8*)&Asb[rowA * 64 + ((kcl ^ (rowA & 7)) << 3)];
        const int rowB = wc + t2 * 16 + fr;
        bfr[t2] = *(const bf16x8*)&Bsb[rowB * 64 + ((kcl ^ (rowB & 7)) << 3)];
      }
      #pragma unroll
      for (int mi = 0; mi < 4; mi++)
        #pragma unroll
        for (int ni = 0; ni < 4; ni++)
          acc[mi][ni] = __builtin_amdgcn_mfma_f32_16x16x32_bf16(af[mi], bfr[ni], acc[mi][ni], 0, 0, 0);
    }
  }

  #pragma unroll
  for (int mi = 0; mi < 4; mi++) {
    #pragma unroll
    for (int reg = 0; reg < 4; reg++) {
      const int m = m0 + wr + mi * 16 + fq * 4 + reg;
      if (MODE == 0) {
        #pragma unroll
        for (int ni = 0; ni < 4; ni++) {
          const int n = n0 + wc + ni * 16 + fr;
          const float r = fmaxf(acc[mi][ni][reg] + biasz[n], 0.f);
          h1out[(size_t)z * CAP_ * FOURC + (size_t)m * FOURC + n] = f2b(r * r);
        }
      } else {
        const int tok = (m < Ne) ? slots[(size_t)e * CAP_ + m] : -1;
        if (tok >= 0) {
          const float gg = gate[tok];
          #pragma unroll
          for (int ni = 0; ni < 4; ni++) {
            const int n = n0 + wc + ni * 16 + fr;
            fout[(size_t)tok * C_ + n] += (acc[mi][ni][reg] + biasz[n]) * gg;
          }
        }
      }
    }
  }
}

// ---------------- launcher ----------------
extern "C" void kernel_launch(void* const* d_in, const int* in_sizes, int n_in,
                              void* d_out, int out_size, void* d_ws, size_t ws_size,
                              hipStream_t stream) {
  const float* x        = (const float*)d_in[0];
  const float* x0       = (const float*)d_in[1];
  const float* noise    = (const float*)d_in[2];
  const float* lambdas  = (const float*)d_in[3];
  // d_in[4] = lamb: (1-lamb)*v + lamb*v == v -> unused
  const float* qkv_w    = (const float*)d_in[5];
  const float* c_proj_w = (const float*)d_in[6];
  const float* c_proj_b = (const float*)d_in[7];
  const float* router_w = (const float*)d_in[8];
  const float* router_b = (const float*)d_in[9];
  const float* noise_w  = (const float*)d_in[10];
  const float* noise_b  = (const float*)d_in[11];
  const float* ew1      = (const float*)d_in[12];
  const float* eb1      = (const float*)d_in[13];
  const float* ew2      = (const float*)d_in[14];
  const float* eb2      = (const float*)d_in[15];
  float* out = (float*)d_out;
  float* ws  = (float*)d_ws;

  float* xr  = ws + OFF_XR;
  float* h   = ws + OFF_H;
  int*   eid    = (int*)(ws + OFF_MISC);
  float* gate0  = ws + OFF_MISC + 4096;
  int*   slots  = (int*)(ws + OFF_MISC + 8192);
  int*   counts = (int*)(ws + OFF_MISC + 16384);
  float* a   = ws + OFF_A;
  float* ob  = ws + OFF_O;
  float* qb  = ws + OFF_Q;
  float* kb  = ws + OFF_K;
  float* vb  = ws + OFF_V;

  // 1) x' = l0*x + l1*x0 ; a = rmsnorm(x')
  k_norm<<<NTOK, 256, 0, stream>>>(x, x0, lambdas, xr, a);
  // 2) qkv = a @ qkv_w^T, scattered into head layout
  k_gemm<0><<<dim3(24, 32), 256, 0, stream>>>(a, qkv_w, nullptr, 1024, 1024, 1024,
      nullptr, nullptr, qb, kb, vb);
  // 3) per-head rmsnorm + rotary on q,k
  k_qkrot<<<dim3(16384, 2), 256, 0, stream>>>(qb, kb);
  // 4) causal attention (register-tiled, named-scalar only)
  k_attn<<<1024, 256, 0, stream>>>(qb, kb, vb, ob);
  // 5) x2 = x' + o @ c_proj_w^T + b  -> d_out
  k_gemm<1><<<dim3(8, 32), 256, 0, stream>>>(ob, c_proj_w, out, 1024, 1024, 1024,
      c_proj_b, xr, nullptr, nullptr, nullptr);
  // 6) h = rmsnorm(x2)
  k_norm<<<NTOK, 256, 0, stream>>>(out, nullptr, nullptr, nullptr, h);
  // 7) router decisions
  k_router<<<NTOK, 256, 0, stream>>>(h, router_w, router_b, noise_w, noise_b,
                                     noise, eid, gate0);
  // 8) ordered compaction into per-expert slot lists
  k_assign<<<1, 256, 0, stream>>>(eid, slots, counts);

  // 9) expert FFNs in bf16 MFMA
  float* exbase = ws + OFF_A;
  unsigned short* h_b = (unsigned short*)exbase;
  float* chunkbase = exbase + 2097152;
  const size_t ws_floats = ws_size / 4;
  long avail = (long)ws_floats - (long)(OFF_A + 2097152);
  int chunk = (int)(avail / (3L * 2097152));
  if (chunk < 1) chunk = 1;
  if (chunk > E_) chunk = E_;

  k_cast<<<2048, 256, 0, stream>>>(h, h_b, 1048576);

  for (int eb = 0; eb < E_; eb += chunk) {
    const int ce = (E_ - eb < chunk) ? (E_ - eb) : chunk;
    unsigned short* ew1b = (unsigned short*)chunkbase;
    unsigned short* ew2b = (unsigned short*)(chunkbase + (size_t)chunk * 2097152);
    unsigned short* h1b  = (unsigned short*)(chunkbase + (size_t)2 * chunk * 2097152);
    k_cast<<<2048, 256, 0, stream>>>(ew1 + (size_t)eb * 4194304, ew1b, ce * 1048576);
    k_cast<<<2048, 256, 0, stream>>>(ew2 + (size_t)eb * 4194304, ew2b, ce * 1048576);
    k_mgemm<0><<<dim3(32, 8, ce), 256, 0, stream>>>(h_b, ew1b, 1024, 1024, 1024,
        eb1, h1b, nullptr, slots, counts, nullptr, eb);
    k_mgemm<1><<<dim3(8, 8, ce), 256, 0, stream>>>(h1b, ew2b, 4096, 4096, 4096,
        eb2, nullptr, out, slots, counts, gate0, eb);
  }
}